// Round 15
// baseline (126.134 us; speedup 1.0000x reference)
//
#include <hip/hip_runtime.h>
#include <cstdint>
#include <cstddef>

typedef __bf16 bf16;
typedef bf16 bf16x8 __attribute__((ext_vector_type(8)));
typedef float f32x4 __attribute__((ext_vector_type(4)));

typedef __attribute__((address_space(1))) void as1_void;
typedef __attribute__((address_space(3))) void as3_void;

__device__ __forceinline__ void gload16(const void* g, void* l) {
  __builtin_amdgcn_global_load_lds((const as1_void*)g, (as3_void*)l, 16, 0, 0);
}

// ---------------- attention (tiny, exact f32) ----------------
__global__ __launch_bounds__(256) void attn_kernel(
    const float* __restrict__ ref, const float* __restrict__ w1,
    const float* __restrict__ w2, const float* __restrict__ b2,
    const float* __restrict__ bias, float* __restrict__ attn,
    float* __restrict__ aggb) {
  const int b = blockIdx.x, t = threadIdx.x;
  __shared__ float pooled[256];
  __shared__ float hsh[65];
  __shared__ float ash[4];
  {
    const float* r = ref + ((size_t)b * 256 + t) * 64;
    float s = 0.f;
    #pragma unroll
    for (int l = 0; l < 64; l += 4) {
      float4 v = *(const float4*)(r + l);
      s += v.x + v.y + v.z + v.w;
    }
    pooled[t] = s * (1.0f / 64.0f);
  }
  __syncthreads();
  if (t < 65) {
    const float* w = w1 + t * 256;
    float s = 0.f;
    for (int p = 0; p < 256; ++p) s += pooled[p] * w[p];
    hsh[t] = fmaxf(s, 0.f);
  }
  __syncthreads();
  if (t == 0) {
    float lg[4];
    for (int k = 0; k < 4; ++k) {
      float s = b2[k];
      for (int j = 0; j < 65; ++j) s += hsh[j] * w2[k * 65 + j];
      lg[k] = s * (1.0f / 34.0f);
    }
    float m = fmaxf(fmaxf(lg[0], lg[1]), fmaxf(lg[2], lg[3]));
    float e[4], se = 0.f;
    for (int k = 0; k < 4; ++k) { e[k] = expf(lg[k] - m); se += e[k]; }
    float inv = 1.0f / se;
    for (int k = 0; k < 4; ++k) { float a = e[k] * inv; ash[k] = a; attn[b * 4 + k] = a; }
  }
  __syncthreads();
  {
    float s = 0.f;
    for (int k = 0; k < 4; ++k) s += ash[k] * bias[k * 256 + t];
    aggb[b * 256 + t] = s;
  }
}

// ---------------- weight aggregation -> bf16, [b][o][s*256+i] ----------------
__global__ __launch_bounds__(256) void aggw_kernel(
    const float* __restrict__ weight, const float* __restrict__ attn,
    bf16* __restrict__ Wagg) {
  const int o = blockIdx.x, b = blockIdx.y, i = threadIdx.x;
  const float a0 = attn[b * 4 + 0], a1 = attn[b * 4 + 1];
  const float a2 = attn[b * 4 + 2], a3 = attn[b * 4 + 3];
  const size_t ks = (size_t)256 * 256 * 3;
  const float* w = weight + ((size_t)o * 256 + i) * 3;
  bf16* dst = Wagg + ((size_t)(b * 256 + o)) * 768 + i;
  #pragma unroll
  for (int s = 0; s < 3; ++s) {
    float v = a0 * w[s] + a1 * w[ks + s] + a2 * w[2 * ks + s] + a3 * w[3 * ks + s];
    dst[s * 256] = (bf16)v;
  }
}

// ---------------- main conv-as-GEMM, 128x128 tile, K=768 ----------------
// R5 anchor with X staging moved ENTIRELY into the i-block boundary
// (load + cvt + transposed ds_write in one lambda, xv/ev lambda-local).
// No registers held across the MFMA phases beyond frags + acc => natural
// unified demand ~126-140 <= 170 => 3 blocks/CU WITHOUT any launch-bounds
// cap (the R3/R6/R7 spill trap). Exposed boundary load latency is covered
// by the other resident blocks. Everything else is R5-verbatim.
__global__ __launch_bounds__(256) void conv_kernel(
    const float* __restrict__ x, const bf16* __restrict__ Wagg,
    const float* __restrict__ aggb, float* __restrict__ out) {
  __shared__ bf16 Wl[2][128 * 64];   // 32 KB (double-buffered per step)
  __shared__ bf16 Xl[130 * 64];      // 16.25 KB (single, swaps per i-block)
  const int tid = threadIdx.x;
  const int lane = tid & 63, wid = tid >> 6;
  // XCD swizzle: 2048 blocks, 8 XCDs -> consecutive swz ids per XCD = 1 batch.
  const int bid = blockIdx.x;
  const int swz = (bid & 7) * 256 + (bid >> 3);
  const int b  = swz >> 6;
  const int ot = (swz >> 5) & 1;
  const int lt = swz & 31;
  const int l0 = lt * 128, o0 = ot * 128;
  const int wm = wid >> 1, wn = wid & 1;
  const float* xb = x + (size_t)b * 256 * 4096;
  const bf16* Wb = Wagg + ((size_t)(b * 256 + o0)) * 768;
  f32x4 acc[4][4] = {};

  // W staging: rows 0..127, 64 k, XOR-swizzled via source addr (R5 verbatim)
  auto stage_w = [&](int step, int buf) {
    const int ss = step % 3, ibb = step / 3;
    const int koff = ss * 256 + ibb * 64;
    #pragma unroll
    for (int r = 0; r < 4; ++r) {
      int c = r * 256 + tid;
      int row = c >> 3, subg = (c & 7) ^ (row & 7);
      gload16(Wb + (size_t)row * 768 + koff + subg * 8,
              (char*)&Wl[buf][0] + (r * 256 + wid * 64) * 16);
    }
  };

  // ---- X staging: load + f32->bf16 cvt + transposed swizzled ds_write,
  //      all at the i-block boundary; xv/ev transient (lambda-local) ----
  const int sg = tid >> 5, lc = tid & 31;
  const float* xmain = xb + ((size_t)sg * 8) * 4096 + l0 + lc * 4;
  const int eg = (tid >> 1) & 7;
  const int erow = (tid & 1) ? 129 : 0;
  const int el = (tid & 1) ? (l0 + 128) : (l0 - 1);
  const bool edge_ok = (el >= 0) && (el < 4096);

  auto stage_x_tile = [&](int ib) {
    float4 xv[8];
    const float* p = xmain + (size_t)ib * 64 * 4096;
    #pragma unroll
    for (int r = 0; r < 8; ++r)
      xv[r] = *(const float4*)(p + (size_t)r * 4096);
    char* base = (char*)&Xl[0];
    #pragma unroll
    for (int q = 0; q < 4; ++q) {
      const int row = lc * 4 + 1 + q;
      bf16x8 pk;
      #pragma unroll
      for (int r = 0; r < 8; ++r) pk[r] = (bf16)(((const float*)&xv[r])[q]);
      *(bf16x8*)(base + row * 128 + ((sg ^ (row & 7)) << 4)) = pk;
    }
    if (tid < 16) {
      bf16x8 pe;
      #pragma unroll
      for (int r = 0; r < 8; ++r) {
        float v = edge_ok ? xb[(size_t)(ib * 64 + eg * 8 + r) * 4096 + el] : 0.f;
        pe[r] = (bf16)v;
      }
      *(bf16x8*)(base + erow * 128 + ((eg ^ (erow & 7)) << 4)) = pe;
    }
  };

  // prologue
  stage_w(0, 0);
  stage_x_tile(0);
  __syncthreads();   // drains W gload_lds (vmcnt) + X ds_writes (lgkm)

  for (int ib = 0; ib < 4; ++ib) {
    #pragma unroll
    for (int s = 0; s < 3; ++s) {
      const int step = ib * 3 + s;
      if (step < 11) stage_w(step + 1, (step + 1) & 1);
      const char* wbuf = (const char*)&Wl[step & 1][0];
      const char* xbuf = (const char*)&Xl[0];
      #pragma unroll
      for (int kk = 0; kk < 2; ++kk) {
        const int sub = (lane >> 4) + kk * 4;
        bf16x8 af[4], bfr[4];
        #pragma unroll
        for (int m = 0; m < 4; ++m) {
          int row = wm * 64 + m * 16 + (lane & 15);
          af[m] = *(const bf16x8*)(wbuf + row * 128 + ((sub ^ (row & 7)) << 4));
        }
        #pragma unroll
        for (int n = 0; n < 4; ++n) {
          int row = wn * 64 + n * 16 + (lane & 15) + s;   // +s = conv shift
          bfr[n] = *(const bf16x8*)(xbuf + row * 128 + ((sub ^ (row & 7)) << 4));
        }
        #pragma unroll
        for (int m = 0; m < 4; ++m)
          #pragma unroll
          for (int n = 0; n < 4; ++n)
            acc[m][n] = __builtin_amdgcn_mfma_f32_16x16x32_bf16(af[m], bfr[n], acc[m][n], 0, 0, 0);
      }
      if (step < 11) __syncthreads();   // per-step barrier (covers W stage drain)
    }
    // all waves past s==2's barrier => Xl reads done; stage next tile here
    if (ib < 3) {
      stage_x_tile(ib + 1);   // load+cvt+write, transient regs; other blocks cover
      __syncthreads();        // writes visible before next i-block's reads
    }
  }

  const int b256 = b * 256;
  #pragma unroll
  for (int m = 0; m < 4; ++m) {
    const int ob = o0 + wm * 64 + m * 16 + ((lane >> 4) << 2);
    float bb[4];
    #pragma unroll
    for (int r = 0; r < 4; ++r) bb[r] = aggb[b256 + ob + r];
    #pragma unroll
    for (int n = 0; n < 4; ++n) {
      const int l = l0 + wn * 64 + n * 16 + (lane & 15);
      f32x4 v = acc[m][n];
      #pragma unroll
      for (int r = 0; r < 4; ++r)
        out[((size_t)(b256 + ob + r)) * 4096 + l] = v[r] + bb[r];
    }
  }
}

extern "C" void kernel_launch(void* const* d_in, const int* in_sizes, int n_in,
                              void* d_out, int out_size, void* d_ws, size_t ws_size,
                              hipStream_t stream) {
  const float* ref    = (const float*)d_in[0];
  const float* x      = (const float*)d_in[1];
  const float* w1     = (const float*)d_in[2];
  const float* w2     = (const float*)d_in[3];
  const float* b2     = (const float*)d_in[4];
  const float* weight = (const float*)d_in[5];
  const float* bias   = (const float*)d_in[6];
  float* out = (float*)d_out;
  char* ws = (char*)d_ws;

  const size_t WAGG_BYTES = (size_t)32 * 256 * 768 * 2;    // 12,582,912
  bf16* Wagg  = (bf16*)ws;
  float* attn = (float*)(ws + WAGG_BYTES);
  float* aggb = (float*)(ws + WAGG_BYTES + 512);

  attn_kernel<<<32, 256, 0, stream>>>(ref, w1, w2, b2, bias, attn, aggb);
  aggw_kernel<<<dim3(256, 32), 256, 0, stream>>>(weight, attn, Wagg);
  conv_kernel<<<2048, 256, 0, stream>>>(x, Wagg, aggb, out);
}

// Round 16
// 119.569 us; speedup vs baseline: 1.0549x; 1.0549x over previous
//
#include <hip/hip_runtime.h>
#include <cstdint>
#include <cstddef>

typedef __bf16 bf16;
typedef bf16 bf16x8 __attribute__((ext_vector_type(8)));
typedef float f32x4 __attribute__((ext_vector_type(4)));

typedef __attribute__((address_space(1))) void as1_void;
typedef __attribute__((address_space(3))) void as3_void;

__device__ __forceinline__ void gload16(const void* g, void* l) {
  __builtin_amdgcn_global_load_lds((const as1_void*)g, (as3_void*)l, 16, 0, 0);
}

// ---------------- attention (tiny, exact f32) ----------------
__global__ __launch_bounds__(256) void attn_kernel(
    const float* __restrict__ ref, const float* __restrict__ w1,
    const float* __restrict__ w2, const float* __restrict__ b2,
    const float* __restrict__ bias, float* __restrict__ attn,
    float* __restrict__ aggb) {
  const int b = blockIdx.x, t = threadIdx.x;
  __shared__ float pooled[256];
  __shared__ float hsh[65];
  __shared__ float ash[4];
  {
    const float* r = ref + ((size_t)b * 256 + t) * 64;
    float s = 0.f;
    #pragma unroll
    for (int l = 0; l < 64; l += 4) {
      float4 v = *(const float4*)(r + l);
      s += v.x + v.y + v.z + v.w;
    }
    pooled[t] = s * (1.0f / 64.0f);
  }
  __syncthreads();
  if (t < 65) {
    const float* w = w1 + t * 256;
    float s = 0.f;
    for (int p = 0; p < 256; ++p) s += pooled[p] * w[p];
    hsh[t] = fmaxf(s, 0.f);
  }
  __syncthreads();
  if (t == 0) {
    float lg[4];
    for (int k = 0; k < 4; ++k) {
      float s = b2[k];
      for (int j = 0; j < 65; ++j) s += hsh[j] * w2[k * 65 + j];
      lg[k] = s * (1.0f / 34.0f);
    }
    float m = fmaxf(fmaxf(lg[0], lg[1]), fmaxf(lg[2], lg[3]));
    float e[4], se = 0.f;
    for (int k = 0; k < 4; ++k) { e[k] = expf(lg[k] - m); se += e[k]; }
    float inv = 1.0f / se;
    for (int k = 0; k < 4; ++k) { float a = e[k] * inv; ash[k] = a; attn[b * 4 + k] = a; }
  }
  __syncthreads();
  {
    float s = 0.f;
    for (int k = 0; k < 4; ++k) s += ash[k] * bias[k * 256 + t];
    aggb[b * 256 + t] = s;
  }
}

// ---------------- weight aggregation -> bf16, [b][o][s*256+i] ----------------
__global__ __launch_bounds__(256) void aggw_kernel(
    const float* __restrict__ weight, const float* __restrict__ attn,
    bf16* __restrict__ Wagg) {
  const int o = blockIdx.x, b = blockIdx.y, i = threadIdx.x;
  const float a0 = attn[b * 4 + 0], a1 = attn[b * 4 + 1];
  const float a2 = attn[b * 4 + 2], a3 = attn[b * 4 + 3];
  const size_t ks = (size_t)256 * 256 * 3;
  const float* w = weight + ((size_t)o * 256 + i) * 3;
  bf16* dst = Wagg + ((size_t)(b * 256 + o)) * 768 + i;
  #pragma unroll
  for (int s = 0; s < 3; ++s) {
    float v = a0 * w[s] + a1 * w[ks + s] + a2 * w[2 * ks + s] + a3 * w[3 * ks + s];
    dst[s * 256] = (bf16)v;
  }
}

// ---------------- main conv-as-GEMM, 128x128 tile, K=768 ----------------
// R15 structure (replay-stable, absmax-proven) with register diet for
// 3 blocks/CU: ALL X-staging locals recomputed inside the lambda (nothing
// loop-carried but acc+frags+few smalls), and compact LDS addressing
// (row&7 == lane&7 since 16&7==0 -> two base offsets + imm multiples of
// 2048 cover all 8 ds_read_b128 per phase). Residency model from the
// 15-round ledger: arch VGPR rounds to 16-granule, +64 acc; <=96 arch
// -> 160/wave -> 3 waves/SIMD (R6 = only round at 27.8% occ, 84 regs).
__global__ __launch_bounds__(256) void conv_kernel(
    const float* __restrict__ x, const bf16* __restrict__ Wagg,
    const float* __restrict__ aggb, float* __restrict__ out) {
  __shared__ bf16 Wl[2][128 * 64];   // 32 KB (double-buffered per step)
  __shared__ bf16 Xl[130 * 64];      // 16.25 KB (single, swaps per i-block)
  const int tid = threadIdx.x;
  const int lane = tid & 63, wid = tid >> 6;
  // XCD swizzle: 2048 blocks, 8 XCDs -> consecutive swz ids per XCD = 1 batch.
  // All block-derived values are SGPR arithmetic (blockIdx is scalar).
  const int bid = blockIdx.x;
  const int swz = (bid & 7) * 256 + (bid >> 3);
  const int b  = swz >> 6;
  const int ot = (swz >> 5) & 1;
  const int lt = swz & 31;
  const int l0 = lt * 128, o0 = ot * 128;
  const int wm = wid >> 1, wn = wid & 1;
  const float* xb = x + (size_t)b * 256 * 4096;
  const bf16* Wb = Wagg + ((size_t)(b * 256 + o0)) * 768;
  f32x4 acc[4][4] = {};

  // W staging: rows 0..127, 64 k, XOR-swizzled via source addr (proven path)
  auto stage_w = [&](int step, int buf) {
    const int ss = step % 3, ibb = step / 3;
    const int koff = ss * 256 + ibb * 64;
    #pragma unroll
    for (int r = 0; r < 4; ++r) {
      int c = r * 256 + tid;
      int row = c >> 3, subg = (c & 7) ^ (row & 7);
      gload16(Wb + (size_t)row * 768 + koff + subg * 8,
              (char*)&Wl[buf][0] + (r * 256 + wid * 64) * 16);
    }
  };

  // ---- X staging at the i-block boundary: EVERYTHING lambda-local ----
  auto stage_x_tile = [&](int ib) {
    const int sg = tid >> 5, lc = tid & 31;
    const float* p = xb + ((size_t)(ib * 64 + sg * 8)) * 4096 + l0 + lc * 4;
    float4 xv[8];
    #pragma unroll
    for (int r = 0; r < 8; ++r)
      xv[r] = *(const float4*)(p + (size_t)r * 4096);
    char* base = (char*)&Xl[0];
    #pragma unroll
    for (int q = 0; q < 4; ++q) {
      const int row = lc * 4 + 1 + q;
      bf16x8 pk;
      #pragma unroll
      for (int r = 0; r < 8; ++r) pk[r] = (bf16)(((const float*)&xv[r])[q]);
      *(bf16x8*)(base + row * 128 + ((sg ^ (row & 7)) << 4)) = pk;
    }
    if (tid < 16) {
      const int eg = (tid >> 1) & 7;
      const int erow = (tid & 1) ? 129 : 0;
      const int el = (tid & 1) ? (l0 + 128) : (l0 - 1);
      const bool ok = (el >= 0) && (el < 4096);
      bf16x8 pe;
      #pragma unroll
      for (int r = 0; r < 8; ++r) {
        float v = ok ? xb[(size_t)(ib * 64 + eg * 8 + r) * 4096 + el] : 0.f;
        pe[r] = (bf16)v;
      }
      *(bf16x8*)(base + erow * 128 + ((eg ^ (erow & 7)) << 4)) = pe;
    }
  };

  // prologue
  stage_w(0, 0);
  stage_x_tile(0);
  __syncthreads();   // drains W gload_lds (vmcnt) + X ds_writes (lgkm)

  for (int ib = 0; ib < 4; ++ib) {
    #pragma unroll
    for (int s = 0; s < 3; ++s) {
      const int step = ib * 3 + s;
      if (step < 11) stage_w(step + 1, (step + 1) & 1);
      const char* wbuf = (const char*)&Wl[step & 1][0] + wm * 8192;
      const char* xbuf = (const char*)&Xl[0] + wn * 8192;
      #pragma unroll
      for (int kk = 0; kk < 2; ++kk) {
        const int sub = (lane >> 4) + kk * 4;
        // row&7 == lane&7 for af (16&7==0); ((lane&15)+s)&7 for bfr.
        const int woff = (lane & 15) * 128 + ((sub ^ (lane & 7)) << 4);
        const int xrow = (lane & 15) + s;
        const int xoff = xrow * 128 + ((sub ^ (xrow & 7)) << 4);
        bf16x8 af[4], bfr[4];
        #pragma unroll
        for (int m = 0; m < 4; ++m)
          af[m] = *(const bf16x8*)(wbuf + woff + m * 2048);
        #pragma unroll
        for (int n = 0; n < 4; ++n)
          bfr[n] = *(const bf16x8*)(xbuf + xoff + n * 2048);
        #pragma unroll
        for (int m = 0; m < 4; ++m)
          #pragma unroll
          for (int n = 0; n < 4; ++n)
            acc[m][n] = __builtin_amdgcn_mfma_f32_16x16x32_bf16(af[m], bfr[n], acc[m][n], 0, 0, 0);
      }
      if (step < 11) __syncthreads();   // per-step barrier (covers W stage drain)
    }
    // all waves past s==2's barrier => Xl reads done; stage next tile here
    if (ib < 3) {
      stage_x_tile(ib + 1);   // transient regs; covered by co-resident blocks
      __syncthreads();        // writes visible before next i-block's reads
    }
  }

  const int b256 = b * 256;
  #pragma unroll
  for (int m = 0; m < 4; ++m) {
    const int ob = o0 + wm * 64 + m * 16 + ((lane >> 4) << 2);
    float bb[4];
    #pragma unroll
    for (int r = 0; r < 4; ++r) bb[r] = aggb[b256 + ob + r];
    #pragma unroll
    for (int n = 0; n < 4; ++n) {
      const int l = l0 + wn * 64 + n * 16 + (lane & 15);
      f32x4 v = acc[m][n];
      #pragma unroll
      for (int r = 0; r < 4; ++r)
        out[((size_t)(b256 + ob + r)) * 4096 + l] = v[r] + bb[r];
    }
  }
}

extern "C" void kernel_launch(void* const* d_in, const int* in_sizes, int n_in,
                              void* d_out, int out_size, void* d_ws, size_t ws_size,
                              hipStream_t stream) {
  const float* ref    = (const float*)d_in[0];
  const float* x      = (const float*)d_in[1];
  const float* w1     = (const float*)d_in[2];
  const float* w2     = (const float*)d_in[3];
  const float* b2     = (const float*)d_in[4];
  const float* weight = (const float*)d_in[5];
  const float* bias   = (const float*)d_in[6];
  float* out = (float*)d_out;
  char* ws = (char*)d_ws;

  const size_t WAGG_BYTES = (size_t)32 * 256 * 768 * 2;    // 12,582,912
  bf16* Wagg  = (bf16*)ws;
  float* attn = (float*)(ws + WAGG_BYTES);
  float* aggb = (float*)(ws + WAGG_BYTES + 512);

  attn_kernel<<<32, 256, 0, stream>>>(ref, w1, w2, b2, bias, attn, aggb);
  aggw_kernel<<<dim3(256, 32), 256, 0, stream>>>(weight, attn, Wagg);
  conv_kernel<<<2048, 256, 0, stream>>>(x, Wagg, aggb, out);
}

// Round 17
// 105.131 us; speedup vs baseline: 1.1998x; 1.1373x over previous
//
#include <hip/hip_runtime.h>
#include <cstdint>
#include <cstddef>

typedef __bf16 bf16;
typedef bf16 bf16x8 __attribute__((ext_vector_type(8)));
typedef float f32x4 __attribute__((ext_vector_type(4)));

typedef __attribute__((address_space(1))) void as1_void;
typedef __attribute__((address_space(3))) void as3_void;

__device__ __forceinline__ void gload16(const void* g, void* l) {
  __builtin_amdgcn_global_load_lds((const as1_void*)g, (as3_void*)l, 16, 0, 0);
}

// ---------------- attention (tiny, exact f32) ----------------
__global__ __launch_bounds__(256) void attn_kernel(
    const float* __restrict__ ref, const float* __restrict__ w1,
    const float* __restrict__ w2, const float* __restrict__ b2,
    const float* __restrict__ bias, float* __restrict__ attn,
    float* __restrict__ aggb) {
  const int b = blockIdx.x, t = threadIdx.x;
  __shared__ float pooled[256];
  __shared__ float hsh[65];
  __shared__ float ash[4];
  {
    const float* r = ref + ((size_t)b * 256 + t) * 64;
    float s = 0.f;
    #pragma unroll
    for (int l = 0; l < 64; l += 4) {
      float4 v = *(const float4*)(r + l);
      s += v.x + v.y + v.z + v.w;
    }
    pooled[t] = s * (1.0f / 64.0f);
  }
  __syncthreads();
  if (t < 65) {
    const float* w = w1 + t * 256;
    float s = 0.f;
    for (int p = 0; p < 256; ++p) s += pooled[p] * w[p];
    hsh[t] = fmaxf(s, 0.f);
  }
  __syncthreads();
  if (t == 0) {
    float lg[4];
    for (int k = 0; k < 4; ++k) {
      float s = b2[k];
      for (int j = 0; j < 65; ++j) s += hsh[j] * w2[k * 65 + j];
      lg[k] = s * (1.0f / 34.0f);
    }
    float m = fmaxf(fmaxf(lg[0], lg[1]), fmaxf(lg[2], lg[3]));
    float e[4], se = 0.f;
    for (int k = 0; k < 4; ++k) { e[k] = expf(lg[k] - m); se += e[k]; }
    float inv = 1.0f / se;
    for (int k = 0; k < 4; ++k) { float a = e[k] * inv; ash[k] = a; attn[b * 4 + k] = a; }
  }
  __syncthreads();
  {
    float s = 0.f;
    for (int k = 0; k < 4; ++k) s += ash[k] * bias[k * 256 + t];
    aggb[b * 256 + t] = s;
  }
}

// ---------------- weight aggregation -> bf16, [b][o][s*256+i] ----------------
__global__ __launch_bounds__(256) void aggw_kernel(
    const float* __restrict__ weight, const float* __restrict__ attn,
    bf16* __restrict__ Wagg) {
  const int o = blockIdx.x, b = blockIdx.y, i = threadIdx.x;
  const float a0 = attn[b * 4 + 0], a1 = attn[b * 4 + 1];
  const float a2 = attn[b * 4 + 2], a3 = attn[b * 4 + 3];
  const size_t ks = (size_t)256 * 256 * 3;
  const float* w = weight + ((size_t)o * 256 + i) * 3;
  bf16* dst = Wagg + ((size_t)(b * 256 + o)) * 768 + i;
  #pragma unroll
  for (int s = 0; s < 3; ++s) {
    float v = a0 * w[s] + a1 * w[ks + s] + a2 * w[2 * ks + s] + a3 * w[3 * ks + s];
    dst[s * 256] = (bf16)v;
  }
}

// ---------------- main conv-as-GEMM, 128x128 tile, K=768 ----------------
// FINAL (R5 anchor, best verified: 105.5 us total, replay-stable).
// Fused X staging (f32 -> bf16 transposed into XOR-swizzled LDS), X tile
// single-buffered (swaps per i-block), W double-buffered via
// global_load_lds, per-step __syncthreads, XCD-aware block swizzle.
// 2 waves/SIMD is the HW residency tier for this register footprint
// (16-round ledger: occupancy invariant at ~20% for VGPR 84..128);
// occupancy/pipelining/geometry variants all regressed or were null.
__global__ __launch_bounds__(256) void conv_kernel(
    const float* __restrict__ x, const bf16* __restrict__ Wagg,
    const float* __restrict__ aggb, float* __restrict__ out) {
  __shared__ bf16 Wl[2][128 * 64];   // 2 x 16 KB (double-buffered per step)
  __shared__ bf16 Xl[130 * 64];      // 16.25 KB (single, swaps per i-block)
  const int tid = threadIdx.x;
  const int lane = tid & 63, wid = tid >> 6;
  // XCD swizzle: 2048 blocks, 8 XCDs -> consecutive swz ids per XCD = 1 batch.
  const int bid = blockIdx.x;
  const int swz = (bid & 7) * 256 + (bid >> 3);
  const int b  = swz >> 6;
  const int ot = (swz >> 5) & 1;
  const int lt = swz & 31;
  const int l0 = lt * 128, o0 = ot * 128;
  const int wm = wid >> 1, wn = wid & 1;
  const float* xb = x + (size_t)b * 256 * 4096;
  const bf16* Wb = Wagg + ((size_t)(b * 256 + o0)) * 768;
  f32x4 acc[4][4] = {};

  // W staging: rows 0..127, 64 k (= koff..koff+63), XOR-swizzled via source addr
  auto stage_w = [&](int step, int buf) {
    const int s = step % 3, ib = step / 3;
    const int koff = s * 256 + ib * 64;
    #pragma unroll
    for (int r = 0; r < 4; ++r) {
      int c = r * 256 + tid;
      int row = c >> 3, subg = (c & 7) ^ (row & 7);
      gload16(Wb + (size_t)row * 768 + koff + subg * 8,
              (char*)&Wl[buf][0] + (r * 256 + wid * 64) * 16);
    }
  };

  // ---- fused X staging (f32 -> bf16 transpose into swizzled LDS) ----
  const int sg = tid >> 5, lc = tid & 31;
  const float* xmain = xb + ((size_t)sg * 8) * 4096 + l0 + lc * 4;
  const int eg = (tid >> 1) & 7;
  const int erow = (tid & 1) ? 129 : 0;
  const int el = (tid & 1) ? (l0 + 128) : (l0 - 1);
  const bool edge_ok = (el >= 0) && (el < 4096);

  float4 xv[8];
  float ev[8];

  auto load_x = [&](int ib) {
    const float* p = xmain + (size_t)ib * 64 * 4096;
    #pragma unroll
    for (int r = 0; r < 8; ++r)
      xv[r] = *(const float4*)(p + (size_t)r * 4096);
    if (tid < 16) {
      #pragma unroll
      for (int r = 0; r < 8; ++r)
        ev[r] = edge_ok ? xb[(size_t)(ib * 64 + eg * 8 + r) * 4096 + el] : 0.f;
    }
  };
  auto write_x = [&]() {
    char* base = (char*)&Xl[0];
    #pragma unroll
    for (int q = 0; q < 4; ++q) {
      const int row = lc * 4 + 1 + q;
      bf16x8 pk;
      #pragma unroll
      for (int r = 0; r < 8; ++r) pk[r] = (bf16)(((const float*)&xv[r])[q]);
      *(bf16x8*)(base + row * 128 + ((sg ^ (row & 7)) << 4)) = pk;
    }
    if (tid < 16) {
      bf16x8 pe;
      #pragma unroll
      for (int r = 0; r < 8; ++r) pe[r] = (bf16)ev[r];
      *(bf16x8*)(base + erow * 128 + ((eg ^ (erow & 7)) << 4)) = pe;
    }
  };

  // prologue
  load_x(0);
  stage_w(0, 0);
  write_x();
  __syncthreads();   // drains W gload_lds (vmcnt) + X ds_writes (lgkm)

  for (int ib = 0; ib < 4; ++ib) {
    if (ib < 3) load_x(ib + 1);          // issue next global loads early (T14)
    const char* xbuf = (const char*)&Xl[0];
    #pragma unroll
    for (int s = 0; s < 3; ++s) {
      const int step = ib * 3 + s;
      if (step < 11) stage_w(step + 1, (step + 1) & 1);
      const char* wbuf = (const char*)&Wl[step & 1][0];
      #pragma unroll
      for (int kk = 0; kk < 2; ++kk) {
        const int sub = (lane >> 4) + kk * 4;
        bf16x8 af[4], bfr[4];
        #pragma unroll
        for (int m = 0; m < 4; ++m) {
          int row = wm * 64 + m * 16 + (lane & 15);
          af[m] = *(const bf16x8*)(wbuf + row * 128 + ((sub ^ (row & 7)) << 4));
        }
        #pragma unroll
        for (int n = 0; n < 4; ++n) {
          int row = wn * 64 + n * 16 + (lane & 15) + s;   // +s = conv shift
          bfr[n] = *(const bf16x8*)(xbuf + row * 128 + ((sub ^ (row & 7)) << 4));
        }
        #pragma unroll
        for (int m = 0; m < 4; ++m)
          #pragma unroll
          for (int n = 0; n < 4; ++n)
            acc[m][n] = __builtin_amdgcn_mfma_f32_16x16x32_bf16(af[m], bfr[n], acc[m][n], 0, 0, 0);
      }
      if (step < 11) __syncthreads();   // per-step barrier (covers W stage drain)
    }
    // all waves are past s==2's barrier => done reading Xl for this ib
    if (ib < 3) {
      write_x();        // bf16-convert + transposed ds_write of next X tile
      __syncthreads();  // writes visible before next i-block's reads
    }
  }

  const int b256 = b * 256;
  #pragma unroll
  for (int m = 0; m < 4; ++m) {
    const int ob = o0 + wm * 64 + m * 16 + ((lane >> 4) << 2);
    float bb[4];
    #pragma unroll
    for (int r = 0; r < 4; ++r) bb[r] = aggb[b256 + ob + r];
    #pragma unroll
    for (int n = 0; n < 4; ++n) {
      const int l = l0 + wn * 64 + n * 16 + (lane & 15);
      f32x4 v = acc[m][n];
      #pragma unroll
      for (int r = 0; r < 4; ++r)
        out[((size_t)(b256 + ob + r)) * 4096 + l] = v[r] + bb[r];
    }
  }
}

extern "C" void kernel_launch(void* const* d_in, const int* in_sizes, int n_in,
                              void* d_out, int out_size, void* d_ws, size_t ws_size,
                              hipStream_t stream) {
  const float* ref    = (const float*)d_in[0];
  const float* x      = (const float*)d_in[1];
  const float* w1     = (const float*)d_in[2];
  const float* w2     = (const float*)d_in[3];
  const float* b2     = (const float*)d_in[4];
  const float* weight = (const float*)d_in[5];
  const float* bias   = (const float*)d_in[6];
  float* out = (float*)d_out;
  char* ws = (char*)d_ws;

  const size_t WAGG_BYTES = (size_t)32 * 256 * 768 * 2;    // 12,582,912
  bf16* Wagg  = (bf16*)ws;
  float* attn = (float*)(ws + WAGG_BYTES);
  float* aggb = (float*)(ws + WAGG_BYTES + 512);

  attn_kernel<<<32, 256, 0, stream>>>(ref, w1, w2, b2, bias, attn, aggb);
  aggw_kernel<<<dim3(256, 32), 256, 0, stream>>>(weight, attn, Wagg);
  conv_kernel<<<2048, 256, 0, stream>>>(x, Wagg, aggb, out);
}